// Round 14
// baseline (353.907 us; speedup 1.0000x reference)
//
#include <hip/hip_runtime.h>

#define N_NODES 50000
#define N_EDGES 800000
#define C 128
#define BN_EPS 1e-5f
#define GB 2048   // gather blocks. Ledger: simple-loop GB=1024 = 100us (R2,R12);
                  // THIS round isolates GB=2048 with the SAME loop (R10/R11 confounded).
#define SCB 196   // scan blocks: 196*256 = 50176 >= N_NODES

// ---- workspace layout (aligned to 256B) ----
static constexpr size_t alignup(size_t v) { return (v + 255) & ~(size_t)255; }
static constexpr size_t XS_OFF   = 0;
static constexpr size_t XS_BYTES = (size_t)N_NODES * C * sizeof(float);      // 25.6 MB
static constexpr size_t DEG_OFF  = alignup(XS_OFF + XS_BYTES);               // int deg -> float dinv (in place)
static constexpr size_t DEG_BYTES= (size_t)N_NODES * sizeof(int);
static constexpr size_t ROW_OFF  = alignup(DEG_OFF + DEG_BYTES);             // rowstart[int x N_NODES]
static constexpr size_t ROW_BYTES= (size_t)N_NODES * sizeof(int);
static constexpr size_t SRC_OFF  = alignup(ROW_OFF + ROW_BYTES);             // srcs_sorted[int x N_EDGES]
static constexpr size_t SRC_BYTES= (size_t)N_EDGES * sizeof(int);
static constexpr size_t SUM_OFF  = alignup(SRC_OFF + SRC_BYTES);             // sums[128]+sumsq[128]
static constexpr size_t SUM_BYTES= (size_t)2 * C * sizeof(float);
static constexpr size_t BS_OFF   = alignup(SUM_OFF + SUM_BYTES);             // bsum[SCB], boff[SCB]
static constexpr size_t BS_BYTES = (size_t)2 * SCB * sizeof(int);
static constexpr size_t WT_OFF   = alignup(BS_OFF + BS_BYTES);               // wt_hi, wt_lo (bf16 128x128 each)
static constexpr size_t WT_BYTES = (size_t)2 * C * C * sizeof(short);

using frag_ab = __attribute__((ext_vector_type(8))) short;  // 8 bf16 (4 VGPRs)
using f32x4   = __attribute__((ext_vector_type(4))) float;

__device__ __forceinline__ void atomAddF(float* p, float v) { unsafeAtomicAdd(p, v); }

__device__ __forceinline__ unsigned short f2bf(float f) {   // RNE float->bf16 bits
    unsigned u = __float_as_uint(f);
    return (unsigned short)((u + 0x7fffu + ((u >> 16) & 1u)) >> 16);
}
__device__ __forceinline__ float bf2f(unsigned short h) {
    return __uint_as_float(((unsigned)h) << 16);
}

// ------------------------------------------- degree histogram (4 edges/thread)
__global__ __launch_bounds__(256) void deg_kernel(const int* __restrict__ ei,
                                                  int* __restrict__ degi) {
    int e4 = blockIdx.x * 256 + threadIdx.x;
    if (e4 < N_EDGES / 4) {
        int4 d4 = ((const int4*)(ei + N_EDGES))[e4];   // dst row, 16B-aligned
        atomicAdd(&degi[d4.x], 1);
        atomicAdd(&degi[d4.y], 1);
        atomicAdd(&degi[d4.z], 1);
        atomicAdd(&degi[d4.w], 1);
    }
}

// ------------------------------------------------- 3-phase exclusive scan of degi
__global__ __launch_bounds__(256) void scanA_kernel(const int* __restrict__ degi,
                                                    int* __restrict__ bsum) {
    const int t = threadIdx.x, b = blockIdx.x;
    int i = b * 256 + t;
    int v = (i < N_NODES) ? degi[i] : 0;
    __shared__ int ps[256];
    ps[t] = v; __syncthreads();
    for (int s = 128; s > 0; s >>= 1) { if (t < s) ps[t] += ps[t + s]; __syncthreads(); }
    if (t == 0) bsum[b] = ps[0];
}
__global__ __launch_bounds__(256) void scanB_kernel(const int* __restrict__ bsum,
                                                    int* __restrict__ boff) {
    const int t = threadIdx.x;
    int v = (t < SCB) ? bsum[t] : 0;
    __shared__ int ps[256];
    ps[t] = v; __syncthreads();
    for (int off = 1; off < 256; off <<= 1) {
        int u = (t >= off) ? ps[t - off] : 0;
        __syncthreads(); ps[t] += u; __syncthreads();
    }
    if (t < SCB) boff[t] = ps[t] - v;   // exclusive
}
// scanC also emits dinv = rsqrt(deg+1), overwriting degi in place (each thread
// reads its own degi[i] before the write; no cross-index degi reads here).
__global__ __launch_bounds__(256) void scanC_kernel(const int* __restrict__ degi,
                                                    const int* __restrict__ boff,
                                                    int* __restrict__ rowstart,
                                                    float* __restrict__ dinv) {
    const int t = threadIdx.x, b = blockIdx.x;
    int i = b * 256 + t;
    int v = (i < N_NODES) ? degi[i] : 0;
    __shared__ int ps[256];
    ps[t] = v; __syncthreads();
    for (int off = 1; off < 256; off <<= 1) {
        int u = (t >= off) ? ps[t - off] : 0;
        __syncthreads(); ps[t] += u; __syncthreads();
    }
    if (i < N_NODES) {
        rowstart[i] = boff[b] + ps[t] - v;   // exclusive start
        dinv[i] = rsqrtf((float)v + 1.0f);
    }
}

// -------------------- fill: place src of each edge into dst-sorted position.
// 4 edges/thread (int4 index loads). rowstart is consumed as cursors;
// post-fill rowstart[d] == original rowstart[d+1].
__global__ __launch_bounds__(256) void fill_kernel(const int* __restrict__ ei,
                                                   int* __restrict__ rowstart,
                                                   int* __restrict__ srcs) {
    int e4 = blockIdx.x * 256 + threadIdx.x;
    if (e4 < N_EDGES / 4) {
        int4 d4 = ((const int4*)(ei + N_EDGES))[e4];
        int4 s4 = ((const int4*)ei)[e4];
        int p0 = atomicAdd(&rowstart[d4.x], 1); srcs[p0] = s4.x;
        int p1 = atomicAdd(&rowstart[d4.y], 1); srcs[p1] = s4.y;
        int p2 = atomicAdd(&rowstart[d4.z], 1); srcs[p2] = s4.z;
        int p3 = atomicAdd(&rowstart[d4.w], 1); srcs[p3] = s4.w;
    }
}

// ---------------- W -> W^T, split to bf16 hi/lo (done once per call; 16K elems)
__global__ __launch_bounds__(256) void wconv_kernel(const float* __restrict__ w,
                                                    unsigned short* __restrict__ wt_hi,
                                                    unsigned short* __restrict__ wt_lo) {
    int idx = blockIdx.x * 256 + threadIdx.x;   // 64 blocks * 256 = 16384
    int k = idx >> 7, n = idx & 127;
    float v = w[idx];
    unsigned short h = f2bf(v);
    wt_hi[n * C + k] = h;
    wt_lo[n * C + k] = f2bf(v - bf2f(h));
}

// --------------------- xs = (x @ W) * dinv[row]  via bf16 hi/lo split MFMA
// Block: 256 thr (4 waves), BM=64 rows, N=128, K chunked by 64.
// mfma_f32_16x16x32_bf16: A lane: row=lane&15, k=(lane>>4)*8+j;
//                         B lane: col=lane&15, k=(lane>>4)*8+j  (stage W^T);
//                         D lane: col=lane&15, row=(lane>>4)*4+reg  [m89-verified].
__global__ __launch_bounds__(256) void xw_mfma_kernel(const float* __restrict__ x,
                                                      const unsigned short* __restrict__ wt_hi,
                                                      const unsigned short* __restrict__ wt_lo,
                                                      const float* __restrict__ dinv,
                                                      float* __restrict__ xs) {
    __shared__ unsigned short Ah[64][72], Al[64][72];    // 9216 B each
    __shared__ unsigned short Bh[128][72], Bl[128][72];  // 18432 B each; total 55.3 KB
    const int t    = threadIdx.x;
    const int wv   = t >> 6;
    const int lane = t & 63;
    const int lr   = lane & 15;       // frag row/col
    const int kg   = lane >> 4;       // k-group (0..3)
    const int row0 = blockIdx.x * 64;

    f32x4 acc[8] = {};   // 8 n-tiles of 16, rows wv*16..wv*16+15

    for (int kt = 0; kt < C; kt += 64) {
        __syncthreads();   // protect LDS from previous chunk's readers
        // stage A: rows 0..63, k = kt..kt+63. thread: r = t>>2, 16-k chunk c16 = t&3
        {
            const int r = t >> 2, c16 = t & 3;
            const int gr = row0 + r;
            const float* xp = x + (size_t)gr * C + kt + c16 * 16;
#pragma unroll
            for (int q = 0; q < 4; ++q) {
                float4 v = make_float4(0.f, 0.f, 0.f, 0.f);
                if (gr < N_NODES) v = *(const float4*)(xp + q * 4);
                unsigned short h0 = f2bf(v.x), h1 = f2bf(v.y), h2 = f2bf(v.z), h3 = f2bf(v.w);
                ushort4 hv = make_ushort4(h0, h1, h2, h3);
                ushort4 lv = make_ushort4(f2bf(v.x - bf2f(h0)), f2bf(v.y - bf2f(h1)),
                                          f2bf(v.z - bf2f(h2)), f2bf(v.w - bf2f(h3)));
                *(ushort4*)&Ah[r][c16 * 16 + q * 4] = hv;
                *(ushort4*)&Al[r][c16 * 16 + q * 4] = lv;
            }
        }
        // stage B: n = t>>1 (0..127), half = t&1 -> 32 k values
        {
            const int n = t >> 1, half = t & 1;
            const unsigned short* ph = wt_hi + (size_t)n * C + kt + half * 32;
            const unsigned short* pl = wt_lo + (size_t)n * C + kt + half * 32;
#pragma unroll
            for (int q = 0; q < 4; ++q) {
                *(int4*)&Bh[n][half * 32 + q * 8] = *(const int4*)(ph + q * 8);
                *(int4*)&Bl[n][half * 32 + q * 8] = *(const int4*)(pl + q * 8);
            }
        }
        __syncthreads();
#pragma unroll
        for (int ks = 0; ks < 2; ++ks) {
            frag_ab a_h = *(const frag_ab*)&Ah[wv * 16 + lr][ks * 32 + kg * 8];
            frag_ab a_l = *(const frag_ab*)&Al[wv * 16 + lr][ks * 32 + kg * 8];
#pragma unroll
            for (int nt = 0; nt < 8; ++nt) {
                frag_ab b_h = *(const frag_ab*)&Bh[nt * 16 + lr][ks * 32 + kg * 8];
                frag_ab b_l = *(const frag_ab*)&Bl[nt * 16 + lr][ks * 32 + kg * 8];
                acc[nt] = __builtin_amdgcn_mfma_f32_16x16x32_bf16(a_h, b_h, acc[nt], 0, 0, 0);
                acc[nt] = __builtin_amdgcn_mfma_f32_16x16x32_bf16(a_l, b_h, acc[nt], 0, 0, 0);
                acc[nt] = __builtin_amdgcn_mfma_f32_16x16x32_bf16(a_h, b_l, acc[nt], 0, 0, 0);
            }
        }
    }

    // epilogue: D row = (lane>>4)*4 + r, col = lane&15
    float dv[4]; int gm[4];
#pragma unroll
    for (int r = 0; r < 4; ++r) {
        gm[r] = row0 + wv * 16 + kg * 4 + r;
        dv[r] = (gm[r] < N_NODES) ? dinv[gm[r]] : 0.f;
    }
#pragma unroll
    for (int nt = 0; nt < 8; ++nt)
#pragma unroll
        for (int r = 0; r < 4; ++r)
            if (gm[r] < N_NODES)
                xs[(size_t)gm[r] * C + nt * 16 + lr] = acc[nt][r] * dv[r];
}

// -------- gather: per-dst segmented reduction + self-loop + scale + bias + BN partials
// One 64-lane wave per dst row (grid-stride). Lane owns channels 2*lane, 2*lane+1.
// Loop byte-identical to the 100us R2/R12 measurement; ONLY GB changed (1024->2048).
__global__ __launch_bounds__(256) void gather_kernel(const int* __restrict__ srcs,
                                                     const int* __restrict__ rowstart,
                                                     const float* __restrict__ xs,
                                                     const float* __restrict__ dinv,
                                                     const float* __restrict__ bias,
                                                     float* __restrict__ out,
                                                     float* __restrict__ sums) {
    const int t    = threadIdx.x;
    const int lane = t & 63;
    const int wv   = t >> 6;                   // 4 waves/block
    const float2 bia = ((const float2*)bias)[lane];
    float sx = 0.f, sy = 0.f, qx = 0.f, qy = 0.f;

    for (int d0 = blockIdx.x * 4 + wv; d0 < N_NODES; d0 += GB * 4) {
        const int d  = __builtin_amdgcn_readfirstlane(d0);
        const int r0 = __builtin_amdgcn_readfirstlane(d ? rowstart[d - 1] : 0);
        const int r1 = __builtin_amdgcn_readfirstlane(rowstart[d]);
        float2 acc = ((const float2*)(xs + (size_t)d * C))[lane];   // self-loop term
        int p = r0;
        for (; p + 4 <= r1; p += 4) {
            int s0 = srcs[p], s1 = srcs[p + 1], s2 = srcs[p + 2], s3 = srcs[p + 3];
            float2 a0 = ((const float2*)(xs + (size_t)s0 * C))[lane];
            float2 a1 = ((const float2*)(xs + (size_t)s1 * C))[lane];
            float2 a2 = ((const float2*)(xs + (size_t)s2 * C))[lane];
            float2 a3 = ((const float2*)(xs + (size_t)s3 * C))[lane];
            acc.x += (a0.x + a1.x) + (a2.x + a3.x);
            acc.y += (a0.y + a1.y) + (a2.y + a3.y);
        }
        for (; p < r1; ++p) {
            int s = srcs[p];
            float2 a = ((const float2*)(xs + (size_t)s * C))[lane];
            acc.x += a.x; acc.y += a.y;
        }
        const float di = dinv[d];
        float2 v = make_float2(acc.x * di + bia.x, acc.y * di + bia.y);
        ((float2*)(out + (size_t)d * C))[lane] = v;
        sx += v.x; sy += v.y;
        qx += v.x * v.x; qy += v.y * v.y;
    }

    __shared__ float2 rs[256];
    __shared__ float2 rq[256];
    rs[t] = make_float2(sx, sy);
    rq[t] = make_float2(qx, qy);
    __syncthreads();
    if (t < 64) {
        float2 S = rs[t], Q = rq[t];
#pragma unroll
        for (int i = 1; i < 4; ++i) {
            S.x += rs[t + 64 * i].x; S.y += rs[t + 64 * i].y;
            Q.x += rq[t + 64 * i].x; Q.y += rq[t + 64 * i].y;
        }
        atomAddF(&sums[2 * t + 0], S.x);
        atomAddF(&sums[2 * t + 1], S.y);
        atomAddF(&sums[C + 2 * t + 0], Q.x);
        atomAddF(&sums[C + 2 * t + 1], Q.y);
    }
}

// --------------------------------------------------- BN normalize + ReLU (in place)
__global__ __launch_bounds__(256) void finalize_kernel(const float* __restrict__ sums,
                                                       const float* __restrict__ gamma,
                                                       const float* __restrict__ beta,
                                                       float* __restrict__ out) {
    __shared__ float sc[C];
    __shared__ float sh[C];
    const int t = threadIdx.x;
    if (t < C) {
        const float invN = 1.0f / (float)N_NODES;
        float m   = sums[t] * invN;
        float var = fmaxf(sums[C + t] * invN - m * m, 0.0f);
        float s   = gamma[t] * rsqrtf(var + BN_EPS);
        sc[t] = s;
        sh[t] = beta[t] - m * s;
    }
    __syncthreads();
    size_t i = (size_t)blockIdx.x * 256 + t;   // float4 index
    int c4 = (i & 31) * 4;
    float4 v = ((const float4*)out)[i];
    v.x = fmaxf(v.x * sc[c4 + 0] + sh[c4 + 0], 0.f);
    v.y = fmaxf(v.y * sc[c4 + 1] + sh[c4 + 1], 0.f);
    v.z = fmaxf(v.z * sc[c4 + 2] + sh[c4 + 2], 0.f);
    v.w = fmaxf(v.w * sc[c4 + 3] + sh[c4 + 3], 0.f);
    ((float4*)out)[i] = v;
}

extern "C" void kernel_launch(void* const* d_in, const int* in_sizes, int n_in,
                              void* d_out, int out_size, void* d_ws, size_t ws_size,
                              hipStream_t stream) {
    const float* x      = (const float*)d_in[0];
    const int*   ei     = (const int*)d_in[1];   // [2][N_EDGES]
    const float* weight = (const float*)d_in[2];
    const float* bias   = (const float*)d_in[3];
    const float* gamma  = (const float*)d_in[4];
    const float* beta   = (const float*)d_in[5];

    float*          xs       = (float*)((char*)d_ws + XS_OFF);
    int*            degi     = (int*)  ((char*)d_ws + DEG_OFF);
    float*          dinv     = (float*)((char*)d_ws + DEG_OFF);   // scanC overwrites degi
    int*            rowstart = (int*)  ((char*)d_ws + ROW_OFF);
    int*            srcs     = (int*)  ((char*)d_ws + SRC_OFF);
    float*          sums     = (float*)((char*)d_ws + SUM_OFF);
    int*            bsum     = (int*)  ((char*)d_ws + BS_OFF);
    int*            boff     = bsum + SCB;
    unsigned short* wt_hi    = (unsigned short*)((char*)d_ws + WT_OFF);
    unsigned short* wt_lo    = wt_hi + C * C;

    hipMemsetAsync((char*)d_ws + DEG_OFF, 0, DEG_BYTES, stream);
    hipMemsetAsync((char*)d_ws + SUM_OFF, 0, SUM_BYTES, stream);

    // 0) W -> W^T bf16 hi/lo (independent)
    wconv_kernel<<<(C * C) / 256, 256, 0, stream>>>(weight, wt_hi, wt_lo);
    // 1) dst-degree histogram (4 edges/thread)
    deg_kernel<<<(N_EDGES / 4 + 255) / 256, 256, 0, stream>>>(ei, degi);
    // 2) parallel exclusive scan -> rowstart; scanC also emits dinv
    scanA_kernel<<<SCB, 256, 0, stream>>>(degi, bsum);
    scanB_kernel<<<1, 256, 0, stream>>>(bsum, boff);
    scanC_kernel<<<SCB, 256, 0, stream>>>(degi, boff, rowstart, dinv);
    // 3) CSR fill: srcs sorted by dst (4 edges/thread; rowstart -> row-end cursors)
    fill_kernel<<<(N_EDGES / 4 + 255) / 256, 256, 0, stream>>>(ei, rowstart, srcs);
    // 4) xs = (x @ W) * dinv[row]  (bf16-split MFMA)
    xw_mfma_kernel<<<(N_NODES + 63) / 64, 256, 0, stream>>>(x, wt_hi, wt_lo, dinv, xs);
    // 5) segmented gather-reduce + self-loop + scale + bias + BN partials -> out
    gather_kernel<<<GB, 256, 0, stream>>>(srcs, rowstart, xs, dinv, bias,
                                          (float*)d_out, sums);
    // 6) BN normalize + ReLU
    finalize_kernel<<<(N_NODES * (C / 4)) / 256, 256, 0, stream>>>(sums, gamma, beta,
                                                                   (float*)d_out);
}

// Round 15
// 292.401 us; speedup vs baseline: 1.2103x; 1.2103x over previous
//
#include <hip/hip_runtime.h>

#define N_NODES 50000
#define N_EDGES 800000
#define C 128
#define BN_EPS 1e-5f
#define GB 1024   // gather blocks. Measured: 1024=100us, 2048=143us (R12/R14 clean A/B).
#define SCB 196   // scan blocks: 196*256 = 50176 >= N_NODES

// ---- workspace layout (aligned to 256B) ----
static constexpr size_t alignup(size_t v) { return (v + 255) & ~(size_t)255; }
static constexpr size_t XS_OFF   = 0;
static constexpr size_t XS_BYTES = (size_t)N_NODES * C * sizeof(short);      // 12.8 MB (bf16)
static constexpr size_t DEG_OFF  = alignup(XS_OFF + XS_BYTES);               // int deg -> float dinv (in place)
static constexpr size_t DEG_BYTES= (size_t)N_NODES * sizeof(int);
static constexpr size_t ROW_OFF  = alignup(DEG_OFF + DEG_BYTES);             // rowstart[int x N_NODES]
static constexpr size_t ROW_BYTES= (size_t)N_NODES * sizeof(int);
static constexpr size_t SRC_OFF  = alignup(ROW_OFF + ROW_BYTES);             // srcs_sorted[int x N_EDGES]
static constexpr size_t SRC_BYTES= (size_t)N_EDGES * sizeof(int);
static constexpr size_t SUM_OFF  = alignup(SRC_OFF + SRC_BYTES);             // sums[128]+sumsq[128]
static constexpr size_t SUM_BYTES= (size_t)2 * C * sizeof(float);
static constexpr size_t BS_OFF   = alignup(SUM_OFF + SUM_BYTES);             // bsum[SCB], boff[SCB]
static constexpr size_t BS_BYTES = (size_t)2 * SCB * sizeof(int);
static constexpr size_t WT_OFF   = alignup(BS_OFF + BS_BYTES);               // wt_hi, wt_lo (bf16 128x128 each)
static constexpr size_t WT_BYTES = (size_t)2 * C * C * sizeof(short);

using frag_ab = __attribute__((ext_vector_type(8))) short;  // 8 bf16 (4 VGPRs)
using f32x4   = __attribute__((ext_vector_type(4))) float;

__device__ __forceinline__ void atomAddF(float* p, float v) { unsafeAtomicAdd(p, v); }

__device__ __forceinline__ unsigned short f2bf(float f) {   // RNE float->bf16 bits
    unsigned u = __float_as_uint(f);
    return (unsigned short)((u + 0x7fffu + ((u >> 16) & 1u)) >> 16);
}
__device__ __forceinline__ float bf2f(unsigned short h) {
    return __uint_as_float(((unsigned)h) << 16);
}
// packed pair (lo = channel 2l, hi = channel 2l+1) -> two floats, 1 bit-op each
__device__ __forceinline__ float pk_lo(unsigned u) { return __uint_as_float(u << 16); }
__device__ __forceinline__ float pk_hi(unsigned u) { return __uint_as_float(u & 0xffff0000u); }

// ------------------------------------------- degree histogram (4 edges/thread)
__global__ __launch_bounds__(256) void deg_kernel(const int* __restrict__ ei,
                                                  int* __restrict__ degi) {
    int e4 = blockIdx.x * 256 + threadIdx.x;
    if (e4 < N_EDGES / 4) {
        int4 d4 = ((const int4*)(ei + N_EDGES))[e4];   // dst row, 16B-aligned
        atomicAdd(&degi[d4.x], 1);
        atomicAdd(&degi[d4.y], 1);
        atomicAdd(&degi[d4.z], 1);
        atomicAdd(&degi[d4.w], 1);
    }
}

// ------------------------------------------------- 3-phase exclusive scan of degi
__global__ __launch_bounds__(256) void scanA_kernel(const int* __restrict__ degi,
                                                    int* __restrict__ bsum) {
    const int t = threadIdx.x, b = blockIdx.x;
    int i = b * 256 + t;
    int v = (i < N_NODES) ? degi[i] : 0;
    __shared__ int ps[256];
    ps[t] = v; __syncthreads();
    for (int s = 128; s > 0; s >>= 1) { if (t < s) ps[t] += ps[t + s]; __syncthreads(); }
    if (t == 0) bsum[b] = ps[0];
}
__global__ __launch_bounds__(256) void scanB_kernel(const int* __restrict__ bsum,
                                                    int* __restrict__ boff) {
    const int t = threadIdx.x;
    int v = (t < SCB) ? bsum[t] : 0;
    __shared__ int ps[256];
    ps[t] = v; __syncthreads();
    for (int off = 1; off < 256; off <<= 1) {
        int u = (t >= off) ? ps[t - off] : 0;
        __syncthreads(); ps[t] += u; __syncthreads();
    }
    if (t < SCB) boff[t] = ps[t] - v;   // exclusive
}
// scanC also emits dinv = rsqrt(deg+1), overwriting degi in place.
__global__ __launch_bounds__(256) void scanC_kernel(const int* __restrict__ degi,
                                                    const int* __restrict__ boff,
                                                    int* __restrict__ rowstart,
                                                    float* __restrict__ dinv) {
    const int t = threadIdx.x, b = blockIdx.x;
    int i = b * 256 + t;
    int v = (i < N_NODES) ? degi[i] : 0;
    __shared__ int ps[256];
    ps[t] = v; __syncthreads();
    for (int off = 1; off < 256; off <<= 1) {
        int u = (t >= off) ? ps[t - off] : 0;
        __syncthreads(); ps[t] += u; __syncthreads();
    }
    if (i < N_NODES) {
        rowstart[i] = boff[b] + ps[t] - v;   // exclusive start
        dinv[i] = rsqrtf((float)v + 1.0f);
    }
}

// -------------------- fill: place src of each edge into dst-sorted position.
__global__ __launch_bounds__(256) void fill_kernel(const int* __restrict__ ei,
                                                   int* __restrict__ rowstart,
                                                   int* __restrict__ srcs) {
    int e4 = blockIdx.x * 256 + threadIdx.x;
    if (e4 < N_EDGES / 4) {
        int4 d4 = ((const int4*)(ei + N_EDGES))[e4];
        int4 s4 = ((const int4*)ei)[e4];
        int p0 = atomicAdd(&rowstart[d4.x], 1); srcs[p0] = s4.x;
        int p1 = atomicAdd(&rowstart[d4.y], 1); srcs[p1] = s4.y;
        int p2 = atomicAdd(&rowstart[d4.z], 1); srcs[p2] = s4.z;
        int p3 = atomicAdd(&rowstart[d4.w], 1); srcs[p3] = s4.w;
    }
}

// ---------------- W -> W^T, split to bf16 hi/lo (done once per call; 16K elems)
__global__ __launch_bounds__(256) void wconv_kernel(const float* __restrict__ w,
                                                    unsigned short* __restrict__ wt_hi,
                                                    unsigned short* __restrict__ wt_lo) {
    int idx = blockIdx.x * 256 + threadIdx.x;   // 64 blocks * 256 = 16384
    int k = idx >> 7, n = idx & 127;
    float v = w[idx];
    unsigned short h = f2bf(v);
    wt_hi[n * C + k] = h;
    wt_lo[n * C + k] = f2bf(v - bf2f(h));
}

// --------------------- xs = bf16((x @ W) * dinv[row])  via bf16 hi/lo split MFMA
// Block: 256 thr (4 waves), BM=64 rows, N=128, K chunked by 64.
// mfma_f32_16x16x32_bf16: A lane: row=lane&15, k=(lane>>4)*8+j;
//                         B lane: col=lane&15, k=(lane>>4)*8+j  (stage W^T);
//                         D lane: col=lane&15, row=(lane>>4)*4+reg  [m89-verified].
// Output stored as bf16 (halves gather bytes; output comparison is bf16-granular).
__global__ __launch_bounds__(256) void xw_mfma_kernel(const float* __restrict__ x,
                                                      const unsigned short* __restrict__ wt_hi,
                                                      const unsigned short* __restrict__ wt_lo,
                                                      const float* __restrict__ dinv,
                                                      unsigned short* __restrict__ xs) {
    __shared__ unsigned short Ah[64][72], Al[64][72];    // 9216 B each
    __shared__ unsigned short Bh[128][72], Bl[128][72];  // 18432 B each; total 55.3 KB
    const int t    = threadIdx.x;
    const int wv   = t >> 6;
    const int lane = t & 63;
    const int lr   = lane & 15;       // frag row/col
    const int kg   = lane >> 4;       // k-group (0..3)
    const int row0 = blockIdx.x * 64;

    f32x4 acc[8] = {};   // 8 n-tiles of 16, rows wv*16..wv*16+15

    for (int kt = 0; kt < C; kt += 64) {
        __syncthreads();   // protect LDS from previous chunk's readers
        // stage A: rows 0..63, k = kt..kt+63. thread: r = t>>2, 16-k chunk c16 = t&3
        {
            const int r = t >> 2, c16 = t & 3;
            const int gr = row0 + r;
            const float* xp = x + (size_t)gr * C + kt + c16 * 16;
#pragma unroll
            for (int q = 0; q < 4; ++q) {
                float4 v = make_float4(0.f, 0.f, 0.f, 0.f);
                if (gr < N_NODES) v = *(const float4*)(xp + q * 4);
                unsigned short h0 = f2bf(v.x), h1 = f2bf(v.y), h2 = f2bf(v.z), h3 = f2bf(v.w);
                ushort4 hv = make_ushort4(h0, h1, h2, h3);
                ushort4 lv = make_ushort4(f2bf(v.x - bf2f(h0)), f2bf(v.y - bf2f(h1)),
                                          f2bf(v.z - bf2f(h2)), f2bf(v.w - bf2f(h3)));
                *(ushort4*)&Ah[r][c16 * 16 + q * 4] = hv;
                *(ushort4*)&Al[r][c16 * 16 + q * 4] = lv;
            }
        }
        // stage B: n = t>>1 (0..127), half = t&1 -> 32 k values
        {
            const int n = t >> 1, half = t & 1;
            const unsigned short* ph = wt_hi + (size_t)n * C + kt + half * 32;
            const unsigned short* pl = wt_lo + (size_t)n * C + kt + half * 32;
#pragma unroll
            for (int q = 0; q < 4; ++q) {
                *(int4*)&Bh[n][half * 32 + q * 8] = *(const int4*)(ph + q * 8);
                *(int4*)&Bl[n][half * 32 + q * 8] = *(const int4*)(pl + q * 8);
            }
        }
        __syncthreads();
#pragma unroll
        for (int ks = 0; ks < 2; ++ks) {
            frag_ab a_h = *(const frag_ab*)&Ah[wv * 16 + lr][ks * 32 + kg * 8];
            frag_ab a_l = *(const frag_ab*)&Al[wv * 16 + lr][ks * 32 + kg * 8];
#pragma unroll
            for (int nt = 0; nt < 8; ++nt) {
                frag_ab b_h = *(const frag_ab*)&Bh[nt * 16 + lr][ks * 32 + kg * 8];
                frag_ab b_l = *(const frag_ab*)&Bl[nt * 16 + lr][ks * 32 + kg * 8];
                acc[nt] = __builtin_amdgcn_mfma_f32_16x16x32_bf16(a_h, b_h, acc[nt], 0, 0, 0);
                acc[nt] = __builtin_amdgcn_mfma_f32_16x16x32_bf16(a_l, b_h, acc[nt], 0, 0, 0);
                acc[nt] = __builtin_amdgcn_mfma_f32_16x16x32_bf16(a_h, b_l, acc[nt], 0, 0, 0);
            }
        }
    }

    // epilogue: D row = (lane>>4)*4 + r, col = lane&15; store bf16
    float dv[4]; int gm[4];
#pragma unroll
    for (int r = 0; r < 4; ++r) {
        gm[r] = row0 + wv * 16 + kg * 4 + r;
        dv[r] = (gm[r] < N_NODES) ? dinv[gm[r]] : 0.f;
    }
#pragma unroll
    for (int nt = 0; nt < 8; ++nt)
#pragma unroll
        for (int r = 0; r < 4; ++r)
            if (gm[r] < N_NODES)
                xs[(size_t)gm[r] * C + nt * 16 + lr] = f2bf(acc[nt][r] * dv[r]);
}

// -------- gather: per-dst segmented reduction + self-loop + scale + bias + BN partials
// One 64-lane wave per dst row (grid-stride). xs rows are bf16 (256 B): lane
// loads ONE dword = channels {2*lane, 2*lane+1}; unpack = 1 bit-op per channel.
// Same proven p+=4 loop shape as the 100us R2/R12 measurement, GB=1024.
__global__ __launch_bounds__(256) void gather_kernel(const int* __restrict__ srcs,
                                                     const int* __restrict__ rowstart,
                                                     const unsigned int* __restrict__ xsu,
                                                     const float* __restrict__ dinv,
                                                     const float* __restrict__ bias,
                                                     float* __restrict__ out,
                                                     float* __restrict__ sums) {
    const int t    = threadIdx.x;
    const int lane = t & 63;
    const int wv   = t >> 6;                   // 4 waves/block
    const int RW = C / 2;                      // 64 dwords per row
    const float2 bia = ((const float2*)bias)[lane];
    float sx = 0.f, sy = 0.f, qx = 0.f, qy = 0.f;

    for (int d0 = blockIdx.x * 4 + wv; d0 < N_NODES; d0 += GB * 4) {
        const int d  = __builtin_amdgcn_readfirstlane(d0);
        const int r0 = __builtin_amdgcn_readfirstlane(d ? rowstart[d - 1] : 0);
        const int r1 = __builtin_amdgcn_readfirstlane(rowstart[d]);
        unsigned su = xsu[(size_t)d * RW + lane];          // self-loop term
        float2 acc = make_float2(pk_lo(su), pk_hi(su));
        int p = r0;
        for (; p + 4 <= r1; p += 4) {
            int s0 = srcs[p], s1 = srcs[p + 1], s2 = srcs[p + 2], s3 = srcs[p + 3];
            unsigned u0 = xsu[(size_t)s0 * RW + lane];
            unsigned u1 = xsu[(size_t)s1 * RW + lane];
            unsigned u2 = xsu[(size_t)s2 * RW + lane];
            unsigned u3 = xsu[(size_t)s3 * RW + lane];
            acc.x += (pk_lo(u0) + pk_lo(u1)) + (pk_lo(u2) + pk_lo(u3));
            acc.y += (pk_hi(u0) + pk_hi(u1)) + (pk_hi(u2) + pk_hi(u3));
        }
        for (; p < r1; ++p) {
            unsigned u = xsu[(size_t)srcs[p] * RW + lane];
            acc.x += pk_lo(u); acc.y += pk_hi(u);
        }
        const float di = dinv[d];
        float2 v = make_float2(acc.x * di + bia.x, acc.y * di + bia.y);
        ((float2*)(out + (size_t)d * C))[lane] = v;
        sx += v.x; sy += v.y;
        qx += v.x * v.x; qy += v.y * v.y;
    }

    __shared__ float2 rs[256];
    __shared__ float2 rq[256];
    rs[t] = make_float2(sx, sy);
    rq[t] = make_float2(qx, qy);
    __syncthreads();
    if (t < 64) {
        float2 S = rs[t], Q = rq[t];
#pragma unroll
        for (int i = 1; i < 4; ++i) {
            S.x += rs[t + 64 * i].x; S.y += rs[t + 64 * i].y;
            Q.x += rq[t + 64 * i].x; Q.y += rq[t + 64 * i].y;
        }
        atomAddF(&sums[2 * t + 0], S.x);
        atomAddF(&sums[2 * t + 1], S.y);
        atomAddF(&sums[C + 2 * t + 0], Q.x);
        atomAddF(&sums[C + 2 * t + 1], Q.y);
    }
}

// --------------------------------------------------- BN normalize + ReLU (in place)
__global__ __launch_bounds__(256) void finalize_kernel(const float* __restrict__ sums,
                                                       const float* __restrict__ gamma,
                                                       const float* __restrict__ beta,
                                                       float* __restrict__ out) {
    __shared__ float sc[C];
    __shared__ float sh[C];
    const int t = threadIdx.x;
    if (t < C) {
        const float invN = 1.0f / (float)N_NODES;
        float m   = sums[t] * invN;
        float var = fmaxf(sums[C + t] * invN - m * m, 0.0f);
        float s   = gamma[t] * rsqrtf(var + BN_EPS);
        sc[t] = s;
        sh[t] = beta[t] - m * s;
    }
    __syncthreads();
    size_t i = (size_t)blockIdx.x * 256 + t;   // float4 index
    int c4 = (i & 31) * 4;
    float4 v = ((const float4*)out)[i];
    v.x = fmaxf(v.x * sc[c4 + 0] + sh[c4 + 0], 0.f);
    v.y = fmaxf(v.y * sc[c4 + 1] + sh[c4 + 1], 0.f);
    v.z = fmaxf(v.z * sc[c4 + 2] + sh[c4 + 2], 0.f);
    v.w = fmaxf(v.w * sc[c4 + 3] + sh[c4 + 3], 0.f);
    ((float4*)out)[i] = v;
}

extern "C" void kernel_launch(void* const* d_in, const int* in_sizes, int n_in,
                              void* d_out, int out_size, void* d_ws, size_t ws_size,
                              hipStream_t stream) {
    const float* x      = (const float*)d_in[0];
    const int*   ei     = (const int*)d_in[1];   // [2][N_EDGES]
    const float* weight = (const float*)d_in[2];
    const float* bias   = (const float*)d_in[3];
    const float* gamma  = (const float*)d_in[4];
    const float* beta   = (const float*)d_in[5];

    unsigned short* xs       = (unsigned short*)((char*)d_ws + XS_OFF);
    int*            degi     = (int*)  ((char*)d_ws + DEG_OFF);
    float*          dinv     = (float*)((char*)d_ws + DEG_OFF);   // scanC overwrites degi
    int*            rowstart = (int*)  ((char*)d_ws + ROW_OFF);
    int*            srcs     = (int*)  ((char*)d_ws + SRC_OFF);
    float*          sums     = (float*)((char*)d_ws + SUM_OFF);
    int*            bsum     = (int*)  ((char*)d_ws + BS_OFF);
    int*            boff     = bsum + SCB;
    unsigned short* wt_hi    = (unsigned short*)((char*)d_ws + WT_OFF);
    unsigned short* wt_lo    = wt_hi + C * C;

    hipMemsetAsync((char*)d_ws + DEG_OFF, 0, DEG_BYTES, stream);
    hipMemsetAsync((char*)d_ws + SUM_OFF, 0, SUM_BYTES, stream);

    // 0) W -> W^T bf16 hi/lo (independent)
    wconv_kernel<<<(C * C) / 256, 256, 0, stream>>>(weight, wt_hi, wt_lo);
    // 1) dst-degree histogram (4 edges/thread)
    deg_kernel<<<(N_EDGES / 4 + 255) / 256, 256, 0, stream>>>(ei, degi);
    // 2) parallel exclusive scan -> rowstart; scanC also emits dinv
    scanA_kernel<<<SCB, 256, 0, stream>>>(degi, bsum);
    scanB_kernel<<<1, 256, 0, stream>>>(bsum, boff);
    scanC_kernel<<<SCB, 256, 0, stream>>>(degi, boff, rowstart, dinv);
    // 3) CSR fill: srcs sorted by dst (4 edges/thread; rowstart -> row-end cursors)
    fill_kernel<<<(N_EDGES / 4 + 255) / 256, 256, 0, stream>>>(ei, rowstart, srcs);
    // 4) xs = bf16((x @ W) * dinv[row])  (bf16-split MFMA)
    xw_mfma_kernel<<<(N_NODES + 63) / 64, 256, 0, stream>>>(x, wt_hi, wt_lo, dinv, xs);
    // 5) segmented gather-reduce + self-loop + scale + bias + BN partials -> out
    gather_kernel<<<GB, 256, 0, stream>>>(srcs, rowstart, (const unsigned int*)xs,
                                          dinv, bias, (float*)d_out, sums);
    // 6) BN normalize + ReLU
    finalize_kernel<<<(N_NODES * (C / 4)) / 256, 256, 0, stream>>>(sums, gamma, beta,
                                                                   (float*)d_out);
}

// Round 17
// 281.027 us; speedup vs baseline: 1.2593x; 1.0405x over previous
//
#include <hip/hip_runtime.h>

#define N_NODES 50000
#define N_EDGES 800000
#define C 128
#define BN_EPS 1e-5f
#define GB 1024   // gather blocks. Measured: 1024=100us, 2048=143us (fp32 rows, R12/R14).
#define SCB 196   // scan blocks: 196*256 = 50176 >= N_NODES
#define WCB 64    // wconv sub-blocks inside fused deg kernel

// ---- workspace layout (aligned to 256B) ----
static constexpr size_t alignup(size_t v) { return (v + 255) & ~(size_t)255; }
static constexpr size_t XS_OFF   = 0;
static constexpr size_t XS_BYTES = (size_t)N_NODES * C * sizeof(short);      // 12.8 MB (bf16)
static constexpr size_t DEG_OFF  = alignup(XS_OFF + XS_BYTES);               // int deg -> float dinv (in place)
static constexpr size_t DEG_BYTES= (size_t)N_NODES * sizeof(int);
static constexpr size_t ROW_OFF  = alignup(DEG_OFF + DEG_BYTES);             // rowstart[int x N_NODES]
static constexpr size_t ROW_BYTES= (size_t)N_NODES * sizeof(int);
static constexpr size_t SRC_OFF  = alignup(ROW_OFF + ROW_BYTES);             // srcs_sorted[int x N_EDGES]
static constexpr size_t SRC_BYTES= (size_t)N_EDGES * sizeof(int);
static constexpr size_t SUM_OFF  = alignup(SRC_OFF + SRC_BYTES);             // sums[128]+sumsq[128]
static constexpr size_t SUM_BYTES= (size_t)2 * C * sizeof(float);
static constexpr size_t BS_OFF   = alignup(SUM_OFF + SUM_BYTES);             // bsum[SCB], boff[SCB]
static constexpr size_t BS_BYTES = (size_t)2 * SCB * sizeof(int);
static constexpr size_t WT_OFF   = alignup(BS_OFF + BS_BYTES);               // wt_hi, wt_lo (bf16 128x128 each)
static constexpr size_t WT_BYTES = (size_t)2 * C * C * sizeof(short);

using frag_ab = __attribute__((ext_vector_type(8))) short;  // 8 bf16 (4 VGPRs)
using f32x4   = __attribute__((ext_vector_type(4))) float;

__device__ __forceinline__ void atomAddF(float* p, float v) { unsafeAtomicAdd(p, v); }

__device__ __forceinline__ unsigned short f2bf(float f) {   // RNE float->bf16 bits
    unsigned u = __float_as_uint(f);
    return (unsigned short)((u + 0x7fffu + ((u >> 16) & 1u)) >> 16);
}
__device__ __forceinline__ float bf2f(unsigned short h) {
    return __uint_as_float(((unsigned)h) << 16);
}
// packed pair (lo = channel 2l, hi = channel 2l+1) -> two floats, 1 bit-op each
__device__ __forceinline__ float pk_lo(unsigned u) { return __uint_as_float(u << 16); }
__device__ __forceinline__ float pk_hi(unsigned u) { return __uint_as_float(u & 0xffff0000u); }

// ------------- fused: W->W^T bf16 hi/lo (blocks 0..63) + degree histogram (rest)
__global__ __launch_bounds__(256) void degwconv_kernel(const int* __restrict__ ei,
                                                       int* __restrict__ degi,
                                                       const float* __restrict__ w,
                                                       unsigned short* __restrict__ wt_hi,
                                                       unsigned short* __restrict__ wt_lo) {
    const int b = blockIdx.x;
    if (b < WCB) {   // W conversion: 64 blocks * 256 = 16384 elements
        int idx = b * 256 + threadIdx.x;
        int k = idx >> 7, n = idx & 127;
        float v = w[idx];
        unsigned short h = f2bf(v);
        wt_hi[n * C + k] = h;
        wt_lo[n * C + k] = f2bf(v - bf2f(h));
        return;
    }
    int e4 = (b - WCB) * 256 + threadIdx.x;
    if (e4 < N_EDGES / 4) {
        int4 d4 = ((const int4*)(ei + N_EDGES))[e4];   // dst row, 16B-aligned
        atomicAdd(&degi[d4.x], 1);
        atomicAdd(&degi[d4.y], 1);
        atomicAdd(&degi[d4.z], 1);
        atomicAdd(&degi[d4.w], 1);
    }
}

// ------------------------------------------------- 3-phase exclusive scan of degi
__global__ __launch_bounds__(256) void scanA_kernel(const int* __restrict__ degi,
                                                    int* __restrict__ bsum) {
    const int t = threadIdx.x, b = blockIdx.x;
    int i = b * 256 + t;
    int v = (i < N_NODES) ? degi[i] : 0;
    __shared__ int ps[256];
    ps[t] = v; __syncthreads();
    for (int s = 128; s > 0; s >>= 1) { if (t < s) ps[t] += ps[t + s]; __syncthreads(); }
    if (t == 0) bsum[b] = ps[0];
}
__global__ __launch_bounds__(256) void scanB_kernel(const int* __restrict__ bsum,
                                                    int* __restrict__ boff) {
    const int t = threadIdx.x;
    int v = (t < SCB) ? bsum[t] : 0;
    __shared__ int ps[256];
    ps[t] = v; __syncthreads();
    for (int off = 1; off < 256; off <<= 1) {
        int u = (t >= off) ? ps[t - off] : 0;
        __syncthreads(); ps[t] += u; __syncthreads();
    }
    if (t < SCB) boff[t] = ps[t] - v;   // exclusive
}
// scanC also emits dinv = rsqrt(deg+1), overwriting degi in place.
__global__ __launch_bounds__(256) void scanC_kernel(const int* __restrict__ degi,
                                                    const int* __restrict__ boff,
                                                    int* __restrict__ rowstart,
                                                    float* __restrict__ dinv) {
    const int t = threadIdx.x, b = blockIdx.x;
    int i = b * 256 + t;
    int v = (i < N_NODES) ? degi[i] : 0;
    __shared__ int ps[256];
    ps[t] = v; __syncthreads();
    for (int off = 1; off < 256; off <<= 1) {
        int u = (t >= off) ? ps[t - off] : 0;
        __syncthreads(); ps[t] += u; __syncthreads();
    }
    if (i < N_NODES) {
        rowstart[i] = boff[b] + ps[t] - v;   // exclusive start
        dinv[i] = rsqrtf((float)v + 1.0f);
    }
}

// -------------------- fill: place src of each edge into dst-sorted position.
__global__ __launch_bounds__(256) void fill_kernel(const int* __restrict__ ei,
                                                   int* __restrict__ rowstart,
                                                   int* __restrict__ srcs) {
    int e4 = blockIdx.x * 256 + threadIdx.x;
    if (e4 < N_EDGES / 4) {
        int4 d4 = ((const int4*)(ei + N_EDGES))[e4];
        int4 s4 = ((const int4*)ei)[e4];
        int p0 = atomicAdd(&rowstart[d4.x], 1); srcs[p0] = s4.x;
        int p1 = atomicAdd(&rowstart[d4.y], 1); srcs[p1] = s4.y;
        int p2 = atomicAdd(&rowstart[d4.z], 1); srcs[p2] = s4.z;
        int p3 = atomicAdd(&rowstart[d4.w], 1); srcs[p3] = s4.w;
    }
}

// --------------------- xs = bf16((x @ W) * dinv[row])  via bf16 hi/lo split MFMA
// Block: 256 thr (4 waves), BM=64 rows, N=128, K chunked by 64.
// mfma_f32_16x16x32_bf16: A lane: row=lane&15, k=(lane>>4)*8+j;
//                         B lane: col=lane&15, k=(lane>>4)*8+j  (stage W^T);
//                         D lane: col=lane&15, row=(lane>>4)*4+reg  [m89-verified].
__global__ __launch_bounds__(256) void xw_mfma_kernel(const float* __restrict__ x,
                                                      const unsigned short* __restrict__ wt_hi,
                                                      const unsigned short* __restrict__ wt_lo,
                                                      const float* __restrict__ dinv,
                                                      unsigned short* __restrict__ xs) {
    __shared__ unsigned short Ah[64][72], Al[64][72];    // 9216 B each
    __shared__ unsigned short Bh[128][72], Bl[128][72];  // 18432 B each; total 55.3 KB
    const int t    = threadIdx.x;
    const int wv   = t >> 6;
    const int lane = t & 63;
    const int lr   = lane & 15;       // frag row/col
    const int kg   = lane >> 4;       // k-group (0..3)
    const int row0 = blockIdx.x * 64;

    f32x4 acc[8] = {};   // 8 n-tiles of 16, rows wv*16..wv*16+15

    for (int kt = 0; kt < C; kt += 64) {
        __syncthreads();   // protect LDS from previous chunk's readers
        // stage A: rows 0..63, k = kt..kt+63. thread: r = t>>2, 16-k chunk c16 = t&3
        {
            const int r = t >> 2, c16 = t & 3;
            const int gr = row0 + r;
            const float* xp = x + (size_t)gr * C + kt + c16 * 16;
#pragma unroll
            for (int q = 0; q < 4; ++q) {
                float4 v = make_float4(0.f, 0.f, 0.f, 0.f);
                if (gr < N_NODES) v = *(const float4*)(xp + q * 4);
                unsigned short h0 = f2bf(v.x), h1 = f2bf(v.y), h2 = f2bf(v.z), h3 = f2bf(v.w);
                ushort4 hv = make_ushort4(h0, h1, h2, h3);
                ushort4 lv = make_ushort4(f2bf(v.x - bf2f(h0)), f2bf(v.y - bf2f(h1)),
                                          f2bf(v.z - bf2f(h2)), f2bf(v.w - bf2f(h3)));
                *(ushort4*)&Ah[r][c16 * 16 + q * 4] = hv;
                *(ushort4*)&Al[r][c16 * 16 + q * 4] = lv;
            }
        }
        // stage B: n = t>>1 (0..127), half = t&1 -> 32 k values
        {
            const int n = t >> 1, half = t & 1;
            const unsigned short* ph = wt_hi + (size_t)n * C + kt + half * 32;
            const unsigned short* pl = wt_lo + (size_t)n * C + kt + half * 32;
#pragma unroll
            for (int q = 0; q < 4; ++q) {
                *(int4*)&Bh[n][half * 32 + q * 8] = *(const int4*)(ph + q * 8);
                *(int4*)&Bl[n][half * 32 + q * 8] = *(const int4*)(pl + q * 8);
            }
        }
        __syncthreads();
#pragma unroll
        for (int ks = 0; ks < 2; ++ks) {
            frag_ab a_h = *(const frag_ab*)&Ah[wv * 16 + lr][ks * 32 + kg * 8];
            frag_ab a_l = *(const frag_ab*)&Al[wv * 16 + lr][ks * 32 + kg * 8];
#pragma unroll
            for (int nt = 0; nt < 8; ++nt) {
                frag_ab b_h = *(const frag_ab*)&Bh[nt * 16 + lr][ks * 32 + kg * 8];
                frag_ab b_l = *(const frag_ab*)&Bl[nt * 16 + lr][ks * 32 + kg * 8];
                acc[nt] = __builtin_amdgcn_mfma_f32_16x16x32_bf16(a_h, b_h, acc[nt], 0, 0, 0);
                acc[nt] = __builtin_amdgcn_mfma_f32_16x16x32_bf16(a_l, b_h, acc[nt], 0, 0, 0);
                acc[nt] = __builtin_amdgcn_mfma_f32_16x16x32_bf16(a_h, b_l, acc[nt], 0, 0, 0);
            }
        }
    }

    // epilogue: D row = (lane>>4)*4 + r, col = lane&15; store bf16
    float dv[4]; int gm[4];
#pragma unroll
    for (int r = 0; r < 4; ++r) {
        gm[r] = row0 + wv * 16 + kg * 4 + r;
        dv[r] = (gm[r] < N_NODES) ? dinv[gm[r]] : 0.f;
    }
#pragma unroll
    for (int nt = 0; nt < 8; ++nt)
#pragma unroll
        for (int r = 0; r < 4; ++r)
            if (gm[r] < N_NODES)
                xs[(size_t)gm[r] * C + nt * 16 + lr] = f2bf(acc[nt][r] * dv[r]);
}

// -------- gather: per-dst segmented reduction + self-loop + scale + bias + BN partials
// One 64-lane wave per dst row (grid-stride). xs rows are bf16 (256 B): lane
// loads ONE dword = channels {2*lane, 2*lane+1}. Unroll 8 (was 4): doubles
// in-flight rows per wave (MLP axis) at the measured-best GB=1024 wave count.
__global__ __launch_bounds__(256) void gather_kernel(const int* __restrict__ srcs,
                                                     const int* __restrict__ rowstart,
                                                     const unsigned int* __restrict__ xsu,
                                                     const float* __restrict__ dinv,
                                                     const float* __restrict__ bias,
                                                     float* __restrict__ out,
                                                     float* __restrict__ sums) {
    const int t    = threadIdx.x;
    const int lane = t & 63;
    const int wv   = t >> 6;                   // 4 waves/block
    const int RW = C / 2;                      // 64 dwords per row
    const float2 bia = ((const float2*)bias)[lane];
    float sx = 0.f, sy = 0.f, qx = 0.f, qy = 0.f;

    for (int d0 = blockIdx.x * 4 + wv; d0 < N_NODES; d0 += GB * 4) {
        const int d  = __builtin_amdgcn_readfirstlane(d0);
        const int r0 = __builtin_amdgcn_readfirstlane(d ? rowstart[d - 1] : 0);
        const int r1 = __builtin_amdgcn_readfirstlane(rowstart[d]);
        unsigned su = xsu[(size_t)d * RW + lane];          // self-loop term
        float2 acc = make_float2(pk_lo(su), pk_hi(su));
        int p = r0;
        for (; p + 8 <= r1; p += 8) {
            int s0 = srcs[p],     s1 = srcs[p + 1], s2 = srcs[p + 2], s3 = srcs[p + 3];
            int s4 = srcs[p + 4], s5 = srcs[p + 5], s6 = srcs[p + 6], s7 = srcs[p + 7];
            unsigned u0 = xsu[(size_t)s0 * RW + lane];
            unsigned u1 = xsu[(size_t)s1 * RW + lane];
            unsigned u2 = xsu[(size_t)s2 * RW + lane];
            unsigned u3 = xsu[(size_t)s3 * RW + lane];
            unsigned u4 = xsu[(size_t)s4 * RW + lane];
            unsigned u5 = xsu[(size_t)s5 * RW + lane];
            unsigned u6 = xsu[(size_t)s6 * RW + lane];
            unsigned u7 = xsu[(size_t)s7 * RW + lane];
            acc.x += ((pk_lo(u0) + pk_lo(u1)) + (pk_lo(u2) + pk_lo(u3)))
                   + ((pk_lo(u4) + pk_lo(u5)) + (pk_lo(u6) + pk_lo(u7)));
            acc.y += ((pk_hi(u0) + pk_hi(u1)) + (pk_hi(u2) + pk_hi(u3)))
                   + ((pk_hi(u4) + pk_hi(u5)) + (pk_hi(u6) + pk_hi(u7)));
        }
        for (; p + 4 <= r1; p += 4) {
            int s0 = srcs[p], s1 = srcs[p + 1], s2 = srcs[p + 2], s3 = srcs[p + 3];
            unsigned u0 = xsu[(size_t)s0 * RW + lane];
            unsigned u1 = xsu[(size_t)s1 * RW + lane];
            unsigned u2 = xsu[(size_t)s2 * RW + lane];
            unsigned u3 = xsu[(size_t)s3 * RW + lane];
            acc.x += (pk_lo(u0) + pk_lo(u1)) + (pk_lo(u2) + pk_lo(u3));
            acc.y += (pk_hi(u0) + pk_hi(u1)) + (pk_hi(u2) + pk_hi(u3));
        }
        for (; p < r1; ++p) {
            unsigned u = xsu[(size_t)srcs[p] * RW + lane];
            acc.x += pk_lo(u); acc.y += pk_hi(u);
        }
        const float di = dinv[d];
        float2 v = make_float2(acc.x * di + bia.x, acc.y * di + bia.y);
        ((float2*)(out + (size_t)d * C))[lane] = v;
        sx += v.x; sy += v.y;
        qx += v.x * v.x; qy += v.y * v.y;
    }

    __shared__ float2 rs[256];
    __shared__ float2 rq[256];
    rs[t] = make_float2(sx, sy);
    rq[t] = make_float2(qx, qy);
    __syncthreads();
    if (t < 64) {
        float2 S = rs[t], Q = rq[t];
#pragma unroll
        for (int i = 1; i < 4; ++i) {
            S.x += rs[t + 64 * i].x; S.y += rs[t + 64 * i].y;
            Q.x += rq[t + 64 * i].x; Q.y += rq[t + 64 * i].y;
        }
        atomAddF(&sums[2 * t + 0], S.x);
        atomAddF(&sums[2 * t + 1], S.y);
        atomAddF(&sums[C + 2 * t + 0], Q.x);
        atomAddF(&sums[C + 2 * t + 1], Q.y);
    }
}

// --------------------------------------------------- BN normalize + ReLU (in place)
__global__ __launch_bounds__(256) void finalize_kernel(const float* __restrict__ sums,
                                                       const float* __restrict__ gamma,
                                                       const float* __restrict__ beta,
                                                       float* __restrict__ out) {
    __shared__ float sc[C];
    __shared__ float sh[C];
    const int t = threadIdx.x;
    if (t < C) {
        const float invN = 1.0f / (float)N_NODES;
        float m   = sums[t] * invN;
        float var = fmaxf(sums[C + t] * invN - m * m, 0.0f);
        float s   = gamma[t] * rsqrtf(var + BN_EPS);
        sc[t] = s;
        sh[t] = beta[t] - m * s;
    }
    __syncthreads();
    size_t i = (size_t)blockIdx.x * 256 + t;   // float4 index
    int c4 = (i & 31) * 4;
    float4 v = ((const float4*)out)[i];
    v.x = fmaxf(v.x * sc[c4 + 0] + sh[c4 + 0], 0.f);
    v.y = fmaxf(v.y * sc[c4 + 1] + sh[c4 + 1], 0.f);
    v.z = fmaxf(v.z * sc[c4 + 2] + sh[c4 + 2], 0.f);
    v.w = fmaxf(v.w * sc[c4 + 3] + sh[c4 + 3], 0.f);
    ((float4*)out)[i] = v;
}

extern "C" void kernel_launch(void* const* d_in, const int* in_sizes, int n_in,
                              void* d_out, int out_size, void* d_ws, size_t ws_size,
                              hipStream_t stream) {
    const float* x      = (const float*)d_in[0];
    const int*   ei     = (const int*)d_in[1];   // [2][N_EDGES]
    const float* weight = (const float*)d_in[2];
    const float* bias   = (const float*)d_in[3];
    const float* gamma  = (const float*)d_in[4];
    const float* beta   = (const float*)d_in[5];

    unsigned short* xs       = (unsigned short*)((char*)d_ws + XS_OFF);
    int*            degi     = (int*)  ((char*)d_ws + DEG_OFF);
    float*          dinv     = (float*)((char*)d_ws + DEG_OFF);   // scanC overwrites degi
    int*            rowstart = (int*)  ((char*)d_ws + ROW_OFF);
    int*            srcs     = (int*)  ((char*)d_ws + SRC_OFF);
    float*          sums     = (float*)((char*)d_ws + SUM_OFF);
    int*            bsum     = (int*)  ((char*)d_ws + BS_OFF);
    int*            boff     = bsum + SCB;
    unsigned short* wt_hi    = (unsigned short*)((char*)d_ws + WT_OFF);
    unsigned short* wt_lo    = wt_hi + C * C;

    hipMemsetAsync((char*)d_ws + DEG_OFF, 0, DEG_BYTES, stream);
    hipMemsetAsync((char*)d_ws + SUM_OFF, 0, SUM_BYTES, stream);

    // 1) fused: W->W^T bf16 hi/lo + dst-degree histogram (4 edges/thread)
    degwconv_kernel<<<WCB + (N_EDGES / 4 + 255) / 256, 256, 0, stream>>>(
        ei, degi, weight, wt_hi, wt_lo);
    // 2) parallel exclusive scan -> rowstart; scanC also emits dinv
    scanA_kernel<<<SCB, 256, 0, stream>>>(degi, bsum);
    scanB_kernel<<<1, 256, 0, stream>>>(bsum, boff);
    scanC_kernel<<<SCB, 256, 0, stream>>>(degi, boff, rowstart, dinv);
    // 3) CSR fill: srcs sorted by dst (4 edges/thread; rowstart -> row-end cursors)
    fill_kernel<<<(N_EDGES / 4 + 255) / 256, 256, 0, stream>>>(ei, rowstart, srcs);
    // 4) xs = bf16((x @ W) * dinv[row])  (bf16-split MFMA)
    xw_mfma_kernel<<<(N_NODES + 63) / 64, 256, 0, stream>>>(x, wt_hi, wt_lo, dinv, xs);
    // 5) segmented gather-reduce + self-loop + scale + bias + BN partials -> out
    gather_kernel<<<GB, 256, 0, stream>>>(srcs, rowstart, (const unsigned int*)xs,
                                          dinv, bias, (float*)d_out, sums);
    // 6) BN normalize + ReLU
    finalize_kernel<<<(N_NODES * (C / 4)) / 256, 256, 0, stream>>>(sums, gamma, beta,
                                                                   (float*)d_out);
}